// Round 2
// baseline (85.750 us; speedup 1.0000x reference)
//
#include <hip/hip_runtime.h>
#include <math.h>

#define NATOMS   4096
#define NRBF     16
#define NHID     64
#define CUTOFF2  25.0f
// ETA = 0.5*(5.0-0.5)/16 = 0.140625 ; 1/(2*ETA^2)
#define INV_2ETA2 25.283950617283951f
#define PI_OVER_CUTOFF 0.62831853071795865f  // pi / 5
#define CAP      96     // per-wave neighbor capacity (mean ~33, >8 sigma)

// ---- cell list (box 40, cutoff 5 -> 8^3 cells, lambda = 8 atoms/cell) ----
#define NC1      8
#define NCELLS   512
#define CELLCAP  32      // Poisson(8): P(cell >= 32) ~ 1e-10 per cell
#define INV_CELL 0.2f    // 1 / 5.0

// ws layout (float units):
//   [0, 4096)                     per-wave (per-atom) energies
//   [4096, 5120)                  cnt[513] ints (cell 512 = dummy, always 0)
//   [5120, 5120 + 512*32*4)       cells: float4[NCELLS][CELLCAP]
#define WS_ENERGY_OFF 0
#define WS_CNT_OFF    4096
#define WS_CELLS_OFF  5120
#define WS_NEED_BYTES ((size_t)(WS_CELLS_OFF + NCELLS * CELLCAP * 4) * 4)

// ============================ cell-list path ============================

// Bin 4096 atoms into padded per-cell lists. cnt[] pre-zeroed by memset.
__global__ __launch_bounds__(256) void bin_kernel(
    const float* __restrict__ pos,
    int* __restrict__ cnt,
    float4* __restrict__ cells)
{
    const int a = blockIdx.x * 256 + threadIdx.x;   // grid = 16 blocks
    const float x = pos[3 * a + 0];
    const float y = pos[3 * a + 1];
    const float z = pos[3 * a + 2];
    const int cx = min((int)(x * INV_CELL), NC1 - 1);
    const int cy = min((int)(y * INV_CELL), NC1 - 1);
    const int cz = min((int)(z * INV_CELL), NC1 - 1);
    const int c  = (cz * NC1 + cy) * NC1 + cx;
    const int slot = atomicAdd(&cnt[c], 1);         // scattered, low contention
    if (slot < CELLCAP) cells[c * CELLCAP + slot] = make_float4(x, y, z, 0.0f);
}

// One wave per atom. Sieve = 27 neighbor cells (2 cells per iteration,
// 32 lanes each; CELLCAP=32 guarantees fit). No LDS staging, no barriers:
// waves are fully independent, per-wave energy -> ws[i].
__global__ __launch_bounds__(256) void short_range_cells_kernel(
    const float* __restrict__ pos,
    const float* __restrict__ centers,
    const int* __restrict__ cnt,
    const float4* __restrict__ cells,
    const float* __restrict__ W1, const float* __restrict__ b1,
    const float* __restrict__ W2, const float* __restrict__ b2,
    const float* __restrict__ W3,
    float* __restrict__ ws)
{
    __shared__ float sdist[4][CAP];     // 1.5 KB
    __shared__ float s_h1[4][NHID];     // 1 KB

    const int tid  = threadIdx.x;
    const int lane = tid & 63;
    const int wave = tid >> 6;
    const int i    = blockIdx.x * 4 + wave;   // this wave's atom

    const float xi = pos[3 * i + 0];
    const float yi = pos[3 * i + 1];
    const float zi = pos[3 * i + 2];
    const int cxi = min((int)(xi * INV_CELL), NC1 - 1);
    const int cyi = min((int)(yi * INV_CELL), NC1 - 1);
    const int czi = min((int)(zi * INV_CELL), NC1 - 1);

    // lane l < 27 owns neighbor cell l (3x3x3); invalid/extra lanes own the
    // dummy cell 512 whose cnt is always 0.
    int nc = NCELLS;
    if (lane < 27) {
        const int cx = cxi + (lane % 3) - 1;
        const int cy = cyi + ((lane / 3) % 3) - 1;
        const int cz = czi + (lane / 9) - 1;
        if ((unsigned)cx < (unsigned)NC1 && (unsigned)cy < (unsigned)NC1 &&
            (unsigned)cz < (unsigned)NC1)
            nc = (cz * NC1 + cy) * NC1 + cx;
    }
    const int mycnt = min(cnt[nc], CELLCAP);   // broadcast loads; cnt[512]==0

    // ---- sieve: 14 iterations x 2 cells; ballot + prefix compaction ----
    const int half = lane >> 5;   // which cell of the pair
    const int idx  = lane & 31;   // slot within that cell
    int base = 0;
#pragma unroll
    for (int t = 0; t < 14; ++t) {
        const int cl = 2 * t + half;               // 0..27 (27 -> dummy lane)
        const int c  = __shfl(nc,    cl, 64);
        const int cn = __shfl(mycnt, cl, 64);
        float sq = 1e30f;
        bool pass = false;
        if (idx < cn) {
            const float4 p = cells[c * CELLCAP + idx];
            const float dx = p.x - xi;
            const float dy = p.y - yi;
            const float dz = p.z - zi;
            sq = dx * dx + dy * dy + dz * dz;
            pass = (sq > 0.0f) && (sq < CUTOFF2);
        }
        const unsigned long long m = __ballot(pass);
        if (pass) {
            const int slot = base + (int)__popcll(m & ((1ull << lane) - 1ull));
            if (slot < CAP) sdist[wave][slot] = sqrtf(sq);
        }
        base += (int)__popcll(m);
    }
    const int count = min(base, CAP);

    // ---- dense RBF, transposed: entry = e0 + (lane>>4), feature = lane&15 ----
    const int   kf   = lane & 15;
    const int   eoff = lane >> 4;
    const float ck   = centers[kf];
    float acc = 0.0f;
    for (int e0 = 0; e0 < count; e0 += 4) {
        const int e = e0 + eoff;
        if (e < count) {
            const float d = sdist[wave][e];
            const float w = 0.5f * (1.0f + __cosf(d * PI_OVER_CUTOFF));
            const float t = d - ck;
            acc += w * __expf(-(t * t) * INV_2ETA2);
        }
    }
    acc += __shfl_xor(acc, 16, 64);
    acc += __shfl_xor(acc, 32, 64);

    // ---- per-wave MLP: lane n owns hidden unit n (NHID == 64) ----
    float h = b1[lane];
#pragma unroll
    for (int k = 0; k < NRBF; ++k)
        h += __shfl(acc, k, 64) * W1[k * NHID + lane];
    h = h / (1.0f + __expf(-h));         // silu
    s_h1[wave][lane] = h;
    // single-wave producer/consumer on own LDS row: program order suffices
    float h2 = b2[lane];
#pragma unroll 8
    for (int m = 0; m < NHID; ++m) h2 += s_h1[wave][m] * W2[m * NHID + lane];
    h2 = h2 / (1.0f + __expf(-h2));      // silu
    float e = h2 * W3[lane];
#pragma unroll
    for (int off = 32; off > 0; off >>= 1) e += __shfl_xor(e, off, 64);
    if (lane == 0) ws[i] = e;
}

// Sum 4096 per-atom energies + NATOMS*b3 -> out[0]. One block.
__global__ __launch_bounds__(256) void reduce4k_kernel(
    const float* __restrict__ ws, const float* __restrict__ b3,
    float* __restrict__ out)
{
    __shared__ float s_part[4];
    const int tid  = threadIdx.x;
    const int lane = tid & 63;
    const int wave = tid >> 6;

    const float4* v4 = (const float4*)ws;
    float s = 0.0f;
#pragma unroll
    for (int k = 0; k < 4; ++k) {
        const float4 v = v4[tid + 256 * k];   // 1024 float4 = 4096 floats
        s += v.x + v.y + v.z + v.w;
    }
#pragma unroll
    for (int off = 32; off > 0; off >>= 1) s += __shfl_xor(s, off, 64);
    if (lane == 0) s_part[wave] = s;
    __syncthreads();
    if (tid == 0)
        out[0] = s_part[0] + s_part[1] + s_part[2] + s_part[3]
               + (float)NATOMS * b3[0];
}

// ==================== fallback: previous verified path ====================
// (verbatim 83 us kernel; used only if ws_size < WS_NEED_BYTES)

#define CHUNK 1024

__global__ __launch_bounds__(256) void short_range_fb_kernel(
    const float* __restrict__ pos,
    const float* __restrict__ centers,
    const float* __restrict__ W1, const float* __restrict__ b1,
    const float* __restrict__ W2, const float* __restrict__ b2,
    const float* __restrict__ W3,
    float* __restrict__ ws)
{
    __shared__ float spos[3 * CHUNK];
    __shared__ float sdist[4][CAP];
    __shared__ float s_h1[4][NHID];
    __shared__ float s_part[4];

    const int tid  = threadIdx.x;
    const int lane = tid & 63;
    const int wave = tid >> 6;
    const int i    = blockIdx.x * 4 + wave;

    float* sx = spos;
    float* sy = spos + CHUNK;
    float* sz = spos + 2 * CHUNK;

    const float xi = pos[3 * i + 0];
    const float yi = pos[3 * i + 1];
    const float zi = pos[3 * i + 2];

    int base = 0;
    for (int c = 0; c < 4; ++c) {
        {
            const float4* src = (const float4*)(pos + c * (3 * CHUNK));
            const float4 v0 = src[3 * tid + 0];
            const float4 v1 = src[3 * tid + 1];
            const float4 v2 = src[3 * tid + 2];
            *(float4*)&sx[4 * tid] = make_float4(v0.x, v0.w, v1.z, v2.y);
            *(float4*)&sy[4 * tid] = make_float4(v0.y, v1.x, v1.w, v2.z);
            *(float4*)&sz[4 * tid] = make_float4(v0.z, v1.y, v2.x, v2.w);
        }
        __syncthreads();
#pragma unroll
        for (int it = 0; it < 4; ++it) {
            const int a = it * 256 + lane * 4;
            const float4 vx = *(const float4*)&sx[a];
            const float4 vy = *(const float4*)&sy[a];
            const float4 vz = *(const float4*)&sz[a];
#pragma unroll
            for (int u = 0; u < 4; ++u) {
                const float dx = ((const float*)&vx)[u] - xi;
                const float dy = ((const float*)&vy)[u] - yi;
                const float dz = ((const float*)&vz)[u] - zi;
                const float sq = dx * dx + dy * dy + dz * dz;
                const bool pass = (sq > 0.0f) && (sq < CUTOFF2);
                const unsigned long long mask = __ballot(pass);
                if (pass) {
                    const int slot = base + (int)__popcll(mask & ((1ull << lane) - 1ull));
                    if (slot < CAP) sdist[wave][slot] = sqrtf(sq);
                }
                base += (int)__popcll(mask);
            }
        }
        __syncthreads();
    }
    const int count = min(base, CAP);

    const int   kf   = lane & 15;
    const int   eoff = lane >> 4;
    const float ck   = centers[kf];
    float acc = 0.0f;
    for (int e0 = 0; e0 < count; e0 += 4) {
        const int e = e0 + eoff;
        if (e < count) {
            const float d = sdist[wave][e];
            const float w = 0.5f * (1.0f + __cosf(d * PI_OVER_CUTOFF));
            const float t = d - ck;
            acc += w * __expf(-(t * t) * INV_2ETA2);
        }
    }
    acc += __shfl_xor(acc, 16, 64);
    acc += __shfl_xor(acc, 32, 64);

    float h = b1[lane];
#pragma unroll
    for (int k = 0; k < NRBF; ++k)
        h += __shfl(acc, k, 64) * W1[k * NHID + lane];
    h = h / (1.0f + __expf(-h));
    s_h1[wave][lane] = h;
    float h2 = b2[lane];
#pragma unroll 8
    for (int m = 0; m < NHID; ++m) h2 += s_h1[wave][m] * W2[m * NHID + lane];
    h2 = h2 / (1.0f + __expf(-h2));
    float e = h2 * W3[lane];
#pragma unroll
    for (int off = 32; off > 0; off >>= 1) e += __shfl_xor(e, off, 64);
    if (lane == 0) s_part[wave] = e;
    __syncthreads();
    if (tid == 0)
        ws[blockIdx.x] = s_part[0] + s_part[1] + s_part[2] + s_part[3];
}

__global__ __launch_bounds__(256) void reduce_fb_kernel(
    const float* __restrict__ ws, const float* __restrict__ b3,
    float* __restrict__ out)
{
    __shared__ float s_part[4];
    const int tid  = threadIdx.x;
    const int lane = tid & 63;
    const int wave = tid >> 6;

    const float4 v = ((const float4*)ws)[tid];
    float s = v.x + v.y + v.z + v.w;
#pragma unroll
    for (int off = 32; off > 0; off >>= 1) s += __shfl_xor(s, off, 64);
    if (lane == 0) s_part[wave] = s;
    __syncthreads();
    if (tid == 0)
        out[0] = s_part[0] + s_part[1] + s_part[2] + s_part[3]
               + (float)NATOMS * b3[0];
}

// ============================== launch ==============================

extern "C" void kernel_launch(void* const* d_in, const int* in_sizes, int n_in,
                              void* d_out, int out_size, void* d_ws, size_t ws_size,
                              hipStream_t stream) {
    const float* pos     = (const float*)d_in[0];
    const float* centers = (const float*)d_in[1];
    const float* W1      = (const float*)d_in[2];
    const float* b1      = (const float*)d_in[3];
    const float* W2      = (const float*)d_in[4];
    const float* b2      = (const float*)d_in[5];
    const float* W3      = (const float*)d_in[6];
    const float* b3      = (const float*)d_in[7];
    float* out = (float*)d_out;
    float* ws  = (float*)d_ws;

    if (ws_size >= WS_NEED_BYTES) {
        int*    cnt   = (int*)(ws + WS_CNT_OFF);
        float4* cells = (float4*)(ws + WS_CELLS_OFF);
        hipMemsetAsync(cnt, 0, (NCELLS + 1) * sizeof(int), stream);
        hipLaunchKernelGGL(bin_kernel, dim3(NATOMS / 256), dim3(256), 0, stream,
                           pos, cnt, cells);
        hipLaunchKernelGGL(short_range_cells_kernel, dim3(NATOMS / 4), dim3(256), 0, stream,
                           pos, centers, cnt, cells, W1, b1, W2, b2, W3,
                           ws + WS_ENERGY_OFF);
        hipLaunchKernelGGL(reduce4k_kernel, dim3(1), dim3(256), 0, stream,
                           ws + WS_ENERGY_OFF, b3, out);
    } else {
        // workspace too small for cell lists: previous verified path
        hipLaunchKernelGGL(short_range_fb_kernel, dim3(NATOMS / 4), dim3(256), 0, stream,
                           pos, centers, W1, b1, W2, b2, W3, ws);
        hipLaunchKernelGGL(reduce_fb_kernel, dim3(1), dim3(256), 0, stream,
                           ws, b3, out);
    }
}